// Round 7
// baseline (148.978 us; speedup 1.0000x reference)
//
#include <hip/hip_runtime.h>
#include <hip/hip_fp16.h>
#include <math.h>

__device__ __forceinline__ float sigm(float x)  { return 1.0f / (1.0f + __expf(-x)); }
__device__ __forceinline__ float siluf(float x) { return x * sigm(x); }

typedef _Float16 half8  __attribute__((ext_vector_type(8)));
typedef _Float16 half4  __attribute__((ext_vector_type(4)));
typedef float    f32x4  __attribute__((ext_vector_type(4)));

// =======================================================================
// R15: zero-LDS register GEMM cores.  Every MFMA fragment is 16 B/lane
// CONTIGUOUS in the prepped layouts, and a wave's 64 lanes (lane=fq*16+fr)
// cover exactly 1024 contiguous bytes -> perfectly coalesced b128 loads
// straight into VGPRs.  No LDS, no barriers, no ds_reads: the compiler
// software-pipelines the fully-unrolled k-loop with its own vmcnt
// scheduling (nothing to drain).  Cost: B refetched per n-dup wave pair
// (~2x B L2 traffic) - B panels are L2-resident, modeled floor ~7us.
// =======================================================================

// ---- 64m x 128n tile, 4 waves as 2m x 2n (qkv) ----
template <int AMODE>
__device__ __forceinline__ void gemm_reg16(
    const __half* __restrict__ A16,
    const __half* __restrict__ Bhi, const __half* __restrict__ Blo,
    int nbs, int m0, int n0, int t, f32x4 (&acc)[2][4])
{
    const int lane = t & 63, wave = t >> 6;
    const int wm = (wave >> 1) << 5, wn = (wave & 1) << 6;
    const int fr = lane & 15, fq = lane >> 4;

    half8 a[2][2], bh[2][4], bl[2][4];

    auto loadA = [&](int kb, int i) -> half8 {
        size_t off;
        if (AMODE == 0)
            off = (((size_t)(kb * 8192 + m0 + wm + (i << 4) + fr)) << 5) + (fq << 3);
        else
            off = (((size_t)(m0 + wm + (i << 4) + fr)) << 8) + (kb << 5) + (fq << 3);
        return *(const half8*)(A16 + off);
    };
    auto loadB = [&](const __half* __restrict__ W, int kb, int ni) -> half8 {
        const size_t off = (((size_t)(kb * nbs + n0 + wn + (ni << 4) + fr)) << 5) + (fq << 3);
        return *(const half8*)(W + off);
    };

#pragma unroll
    for (int i = 0; i < 2; ++i) a[0][i] = loadA(0, i);
#pragma unroll
    for (int ni = 0; ni < 4; ++ni) { bh[0][ni] = loadB(Bhi, 0, ni); bl[0][ni] = loadB(Blo, 0, ni); }

#pragma unroll
    for (int kb = 0; kb < 8; ++kb) {
        const int cur = kb & 1, nxt = cur ^ 1;
        if (kb < 7) {
#pragma unroll
            for (int i = 0; i < 2; ++i) a[nxt][i] = loadA(kb + 1, i);
#pragma unroll
            for (int ni = 0; ni < 4; ++ni) {
                bh[nxt][ni] = loadB(Bhi, kb + 1, ni);
                bl[nxt][ni] = loadB(Blo, kb + 1, ni);
            }
        }
#pragma unroll
        for (int mi = 0; mi < 2; ++mi)
#pragma unroll
            for (int ni = 0; ni < 4; ++ni) {
                acc[mi][ni] = __builtin_amdgcn_mfma_f32_16x16x32_f16(a[cur][mi], bh[cur][ni], acc[mi][ni], 0, 0, 0);
                acc[mi][ni] = __builtin_amdgcn_mfma_f32_16x16x32_f16(a[cur][mi], bl[cur][ni], acc[mi][ni], 0, 0, 0);
            }
    }
}

// ---- 64m x 64n tile, 4 waves all in m (gate/out; A row-major [m][256]) ----
__device__ __forceinline__ void gemm_reg64(
    const __half* __restrict__ A16,
    const __half* __restrict__ Bhi, const __half* __restrict__ Blo,
    int m0, int n0, int t, f32x4 (&acc)[4])
{
    const int lane = t & 63, wave = t >> 6;
    const int wm = wave << 4;
    const int fr = lane & 15, fq = lane >> 4;

    half8 a[2], bh[2][4], bl[2][4];

    auto loadA = [&](int kb) -> half8 {
        const size_t off = (((size_t)(m0 + wm + fr)) << 8) + (kb << 5) + (fq << 3);
        return *(const half8*)(A16 + off);
    };
    auto loadB = [&](const __half* __restrict__ W, int kb, int ni) -> half8 {
        const size_t off = (((size_t)(kb * 256 + n0 + (ni << 4) + fr)) << 5) + (fq << 3);
        return *(const half8*)(W + off);
    };

    a[0] = loadA(0);
#pragma unroll
    for (int ni = 0; ni < 4; ++ni) { bh[0][ni] = loadB(Bhi, 0, ni); bl[0][ni] = loadB(Blo, 0, ni); }

#pragma unroll
    for (int kb = 0; kb < 8; ++kb) {
        const int cur = kb & 1, nxt = cur ^ 1;
        if (kb < 7) {
            a[nxt] = loadA(kb + 1);
#pragma unroll
            for (int ni = 0; ni < 4; ++ni) {
                bh[nxt][ni] = loadB(Bhi, kb + 1, ni);
                bl[nxt][ni] = loadB(Blo, kb + 1, ni);
            }
        }
#pragma unroll
        for (int ni = 0; ni < 4; ++ni) {
            acc[ni] = __builtin_amdgcn_mfma_f32_16x16x32_f16(a[cur], bh[cur][ni], acc[ni], 0, 0, 0);
            acc[ni] = __builtin_amdgcn_mfma_f32_16x16x32_f16(a[cur], bl[cur][ni], acc[ni], 0, 0, 0);
        }
    }
}

// =======================================================================
// Prep (R4 form): x -> f16 k-blocked + wp; weights -> [kb][n][32] hi/lo.
// =======================================================================
__global__ __launch_bounds__(256) void prep_kernel(
    const float* __restrict__ x, const float* __restrict__ Wqkv,
    const float* __restrict__ Wgate, const float* __restrict__ Wout,
    const float* __restrict__ Wwp, const float* __restrict__ bwp,
    __half* __restrict__ xh,
    __half* __restrict__ wqh, __half* __restrict__ wql,
    __half* __restrict__ wgh, __half* __restrict__ wgl,
    __half* __restrict__ woh, __half* __restrict__ wol,
    float* __restrict__ width, float* __restrict__ sharp)
{
    __shared__ float xs[32][260];
    const int t = threadIdx.x;
    const int blk = blockIdx.x;
    if (blk < 256) {
        const int row0 = blk << 5;
        for (int e = t; e < 2048; e += 256) {
            int r = e >> 6, cc = (e & 63) << 2;
            *(float4*)&xs[r][cc] = *(const float4*)&x[(size_t)(row0 + r) * 256 + cc];
        }
        __syncthreads();
        const int r = t >> 3, kb = t & 7;
        __half hibuf[32];
#pragma unroll
        for (int i = 0; i < 32; ++i)
            hibuf[i] = __float2half(xs[r][(kb << 5) + i]);
        const size_t ob = ((size_t)(kb * 8192 + row0 + r)) << 5;
#pragma unroll
        for (int i = 0; i < 4; ++i)
            *(int4*)&xh[ob + (i << 3)] = *(int4*)&hibuf[i << 3];
        // wp: thread (r, n=kb); 4 accumulators break the 256-FMA dep chain
        float a0 = 0.f, a1 = 0.f, a2 = 0.f, a3 = 0.f;
#pragma unroll 4
        for (int k = 0; k < 256; k += 4) {
            a0 += xs[r][k + 0] * Wwp[(k + 0) * 8 + kb];
            a1 += xs[r][k + 1] * Wwp[(k + 1) * 8 + kb];
            a2 += xs[r][k + 2] * Wwp[(k + 2) * 8 + kb];
            a3 += xs[r][k + 3] * Wwp[(k + 3) * 8 + kb];
        }
        const float acc = (a0 + a1) + (a2 + a3);
        float s = sigm(siluf(acc + bwp[kb]));
        const int row = row0 + r;
        if (kb < 4) width[row * 4 + kb] = s * 4.242640687119285f + 0.5f;  // sqrt(18)
        else        sharp[row * 4 + kb - 4] = s * 9.5f + 0.5f;
    } else {
        const float* W; __half *Whi, *Wlo; int N, nb0, ncnt;
        if (blk < 288)      { W = Wqkv;  Whi = wqh; Wlo = wql; N = 768; nb0 = (blk - 256) * 24; ncnt = 24; }
        else if (blk < 296) { W = Wgate; Whi = wgh; Wlo = wgl; N = 256; nb0 = (blk - 288) * 32; ncnt = 32; }
        else                { W = Wout;  Whi = woh; Wlo = wol; N = 256; nb0 = (blk - 296) * 32; ncnt = 32; }
        for (int j = 0; j < ncnt; ++j)
            xs[j][t] = W[(size_t)t * N + nb0 + j];   // t = k row
        __syncthreads();
        for (int c = t; c < ncnt * 8; c += 256) {
            const int j = c >> 3, kb = c & 7;
            __half hibuf[32], lobuf[32];
#pragma unroll
            for (int i = 0; i < 32; ++i) {
                float v = xs[j][(kb << 5) + i];
                __half hv = __float2half(v);
                hibuf[i] = hv;
                lobuf[i] = __float2half(v - __half2float(hv));
            }
            const size_t ob = ((size_t)(kb * N + nb0 + j)) << 5;
#pragma unroll
            for (int i = 0; i < 4; ++i) {
                *(int4*)&Whi[ob + (i << 3)] = *(int4*)&hibuf[i << 3];
                *(int4*)&Wlo[ob + (i << 3)] = *(int4*)&lobuf[i << 3];
            }
        }
    }
}

// =======================================================================
// qkv GEMM (64x128 tiles, 768 blocks, zero-LDS) + fused silu -> rmsnorm
// -> RoPE(pos=head) -> f16 stores.
// =======================================================================
__global__ __launch_bounds__(256, 3) void gemm_qkv(
    const __half* __restrict__ xh,
    const __half* __restrict__ wqh, const __half* __restrict__ wql,
    const float* __restrict__ wq, const float* __restrict__ wk,
    __half* __restrict__ qh, __half* __restrict__ kh, __half* __restrict__ vh)
{
    const int t  = threadIdx.x;
    const int m0 = blockIdx.y << 6, n0 = blockIdx.x << 7;
    f32x4 acc[2][4] = {};
    gemm_reg16<0>(xh, wqh, wql, 768, m0, n0, t, acc);

    const int lane = t & 63, wave = t >> 6;
    const int wm = (wave >> 1) << 5, wn = (wave & 1) << 6;
    const int fr = lane & 15, fq = lane >> 4;
    const int gc0 = n0 + wn;
    const int seg = gc0 >> 8;          // 0=q, 1=k, 2=v
    const int h   = (gc0 >> 6) & 3;
    const int hc0 = h << 6;

#pragma unroll
    for (int mi = 0; mi < 2; ++mi)
#pragma unroll
        for (int ni = 0; ni < 4; ++ni)
#pragma unroll
            for (int r = 0; r < 4; ++r)
                acc[mi][ni][r] = siluf(acc[mi][ni][r]);

    if (seg == 2) {
#pragma unroll
        for (int mi = 0; mi < 2; ++mi)
#pragma unroll
            for (int r = 0; r < 4; ++r) {
                const size_t row = m0 + wm + (mi << 4) + (fq << 2) + r;
#pragma unroll
                for (int ni = 0; ni < 4; ++ni)
                    vh[row * 256 + hc0 + (ni << 4) + fr] = __float2half(acc[mi][ni][r]);
            }
    } else {
        const float* wnorm = seg ? wk : wq;
        float wv[4];
#pragma unroll
        for (int ni = 0; ni < 4; ++ni) wv[ni] = wnorm[(ni << 4) + fr];
        float cs[2], sn[2];
#pragma unroll
        for (int j = 0; j < 2; ++j) {
            const int d = (j << 4) + fr;
            const float freq = powf(10000.f, -(float)d * (1.f / 32.f));
            const float ang = (float)h * freq;    // pos = arange(H) reference quirk
            cs[j] = cosf(ang); sn[j] = sinf(ang);
        }
        __half* dstbase = (seg ? kh : qh);
#pragma unroll
        for (int mi = 0; mi < 2; ++mi)
#pragma unroll
            for (int r = 0; r < 4; ++r) {
                float ss = acc[mi][0][r] * acc[mi][0][r] + acc[mi][1][r] * acc[mi][1][r]
                         + acc[mi][2][r] * acc[mi][2][r] + acc[mi][3][r] * acc[mi][3][r];
                ss += __shfl_xor(ss, 1); ss += __shfl_xor(ss, 2);
                ss += __shfl_xor(ss, 4); ss += __shfl_xor(ss, 8);
                const float rinv = 1.f / sqrtf(ss * (1.f / 64.f) + 1e-6f);
                float xv[4];
#pragma unroll
                for (int ni = 0; ni < 4; ++ni) xv[ni] = acc[mi][ni][r] * rinv * wv[ni];
                const float o0 = xv[0] * cs[0] - xv[2] * sn[0];
                const float o2 = xv[0] * sn[0] + xv[2] * cs[0];
                const float o1 = xv[1] * cs[1] - xv[3] * sn[1];
                const float o3 = xv[1] * sn[1] + xv[3] * cs[1];
                const size_t row = m0 + wm + (mi << 4) + (fq << 2) + r;
                __half* dst = dstbase + row * 256 + hc0;
                dst[fr]      = __float2half(o0);
                dst[16 + fr] = __float2half(o1);
                dst[32 + fr] = __float2half(o2);
                dst[48 + fr] = __float2half(o3);
            }
    }
}

// ---- gate GEMM (64x64 tiles, 512 blocks, zero-LDS) + o-rmsnorm + merge ----
__global__ __launch_bounds__(256, 2) void gemm_gate(
    const __half* __restrict__ vh,
    const __half* __restrict__ wgh, const __half* __restrict__ wgl,
    const float* __restrict__ bias, const float* __restrict__ attn_o,
    const float* __restrict__ sumsq4, const float* __restrict__ w_onorm,
    __half* __restrict__ mh)
{
    const int t  = threadIdx.x;
    const int m0 = blockIdx.y << 6, n0 = blockIdx.x << 6;
    f32x4 acc[4] = {};
    gemm_reg64(vh, wgh, wgl, m0, n0, t, acc);

    const int lane = t & 63, wave = t >> 6;
    const int wm = wave << 4;
    const int fr = lane & 15, fq = lane >> 4;

    float rmsf[4];
#pragma unroll
    for (int r = 0; r < 4; ++r) {
        const int m = m0 + wm + (fq << 2) + r;
        float4 s4 = *(const float4*)&sumsq4[(size_t)m * 4];
        rmsf[r] = 1.f / sqrtf((s4.x + s4.y + s4.z + s4.w) * (1.f / 256.f) + 1e-6f);
    }

#pragma unroll
    for (int ni = 0; ni < 4; ++ni) {
        const int n  = n0 + (ni << 4) + fr;
        const int mb = m0 + wm + (fq << 2);
        const float bb  = bias[n];
        const float won = w_onorm[n];
#pragma unroll
        for (int r = 0; r < 4; ++r) {
            const int m = mb + r;
            const float g  = sigm(siluf(acc[ni][r] + bb));
            const float vv = __half2float(vh[(size_t)m * 256 + n]);
            const float oo = attn_o[(size_t)m * 256 + n] * rmsf[r] * won;
            mh[(size_t)m * 256 + n] = __float2half(g * vv + (1.f - g) * oo);
        }
    }
}

// ---- final GEMM (64x64 tiles, 512 blocks, zero-LDS): out = silu(mh @ W_out) ----
__global__ __launch_bounds__(256, 2) void gemm_out(
    const __half* __restrict__ mh,
    const __half* __restrict__ woh, const __half* __restrict__ wol,
    float* __restrict__ out)
{
    const int t  = threadIdx.x;
    const int m0 = blockIdx.y << 6, n0 = blockIdx.x << 6;
    f32x4 acc[4] = {};
    gemm_reg64(mh, woh, wol, m0, n0, t, acc);

    const int lane = t & 63, wave = t >> 6;
    const int wm = wave << 4;
    const int fr = lane & 15, fq = lane >> 4;
#pragma unroll
    for (int ni = 0; ni < 4; ++ni) {
        const int n  = n0 + (ni << 4) + fr;
        const int mb = m0 + wm + (fq << 2);
#pragma unroll
        for (int r = 0; r < 4; ++r)
            out[(size_t)(mb + r) * 256 + n] = siluf(acc[ni][r]);
    }
}

// =======================================================================
// Patch-GEMM local attention (R1 version: Ksh-staged, windowed n-tiles).
// =======================================================================
#define PT 216   // P / Vt row stride (halves)

__global__ __launch_bounds__(256, 2) void attn_mfma(
    const __half* __restrict__ qh, const __half* __restrict__ kh,
    const __half* __restrict__ vh, const float* __restrict__ width,
    const float* __restrict__ sharp, float* __restrict__ attn_o,
    float* __restrict__ sumsq4)
{
    __shared__ short smem[27648];          // 55296 B
    short* Ksh = smem;                     // [208][64] chunk-swizzled; overlaid by P [64][PT]
    short* Psh = smem;
    short* Vt  = smem + 13824;             // [64 d][PT]

    const int t = threadIdx.x;
    const int lane = t & 63, wave = t >> 6;
    const int fr = lane & 15, fq = lane >> 4;
    const int patch = blockIdx.x, h = blockIdx.y, b = blockIdx.z;
    const int pr0 = (patch >> 3) << 3, pc0 = (patch & 7) << 3;
    const int t0 = (wave * 28) >> 4;       // first n-tile of this wave's window

    float wd[4], sh[4]; int lq[4];
#pragma unroll
    for (int r = 0; r < 4; ++r) {
        const int q = (wave << 4) + (fq << 2) + r;
        lq[r] = (pr0 + (q >> 3)) * 64 + pc0 + (q & 7);
        wd[r] = width[((b << 12) + lq[r]) * 4 + h];
        sh[r] = sharp[((b << 12) + lq[r]) * 4 + h];
    }

    // ---- Q straight into A-frags ----
    const int qrow = (wave << 4) + fr;
    const int lqr = (pr0 + (qrow >> 3)) * 64 + pc0 + (qrow & 7);
    const __half* qptr = qh + (((size_t)(b << 12) + lqr) << 8) + (h << 6) + (fq << 3);
    half8 a0 = *(const half8*)qptr;
    half8 a1 = *(const half8*)(qptr + 32);

    // ---- K/V staging (clamped+select, single drain) ----
    const int srow = t >> 5;
    const int d2 = (t & 31) << 1;
    const size_t cbase = (((size_t)b << 12) * 256) + (size_t)h * 64 + d2;

    unsigned kb[25], vb[25];
#pragma unroll
    for (int p5 = 0; p5 < 25; ++p5) {
        const int prow = p5 * 8 + srow;
        const int pi = prow / 14, pj = prow - pi * 14;
        const int gr = pr0 - 3 + pi, gc = pc0 - 3 + pj;
        const bool ok = (prow < 196) & ((unsigned)gr < 64u) & ((unsigned)gc < 64u);
        const int grc = min(max(gr, 0), 63), gcc = min(max(gc, 0), 63);
        const size_t off = cbase + (size_t)(grc * 64 + gcc) * 256;
        unsigned kv = *(const unsigned*)(kh + off);
        unsigned vv = *(const unsigned*)(vh + off);
        kb[p5] = ok ? kv : 0u;
        vb[p5] = ok ? vv : 0u;
    }

    const int chunk = d2 >> 3, dlo = d2 & 7;
#pragma unroll
    for (int p5 = 0; p5 < 25; ++p5) {
        const int prow = p5 * 8 + srow;
        *(unsigned*)&Ksh[(prow << 6) + ((chunk ^ (prow & 7)) << 3) + dlo] = kb[p5];
        Vt[(d2)     * PT + prow] = (short)(vb[p5] & 0xffffu);
        Vt[(d2 + 1) * PT + prow] = (short)(vb[p5] >> 16);
    }
    // zero Ksh rows 200..207 (read by QK tile 12; never staged)
    if (t < 128) {
        const int rr = 200 + (t >> 4);
        *(unsigned*)&Ksh[(rr << 6) + (((t & 15) ^ ((rr & 7) << 1)) << 2)] = 0u;
    }
    // zero Vt pad cols 196..215
    for (int i = t; i < 64 * 20; i += 256)
        Vt[(i / 20) * PT + 196 + (i % 20)] = 0;
    __syncthreads();

    // ---- QK^T: 8 windowed n-tiles of 16 positions ----
    f32x4 sc[8];
#pragma unroll
    for (int tl = 0; tl < 8; ++tl) {
        const int kr = ((t0 + tl) << 4) + fr;
        half8 b0 = *(const half8*)&Ksh[(kr << 6) + (((0 + fq) ^ (kr & 7)) << 3)];
        half8 b1 = *(const half8*)&Ksh[(kr << 6) + (((4 + fq) ^ (kr & 7)) << 3)];
        f32x4 z = {0.f, 0.f, 0.f, 0.f};
        z = __builtin_amdgcn_mfma_f32_16x16x32_f16(a0, b0, z, 0, 0, 0);
        sc[tl] = __builtin_amdgcn_mfma_f32_16x16x32_f16(a1, b1, z, 0, 0, 0);
    }

    // ---- mask + softmax ----
    float mx[4] = {-3e38f, -3e38f, -3e38f, -3e38f};
#pragma unroll
    for (int tl = 0; tl < 8; ++tl) {
        const int p = ((t0 + tl) << 4) + fr;
        const int pi = p / 14, pj = p - pi * 14;
        const bool pvld = p < 196;
#pragma unroll
        for (int r = 0; r < 4; ++r) {
            const int q = (wave << 4) + (fq << 2) + r;
            const int di = pi - 3 - ((q >> 3) & 7), dj = pj - 3 - (q & 7);
            const bool win = pvld & ((unsigned)(di + 3) <= 6u) & ((unsigned)(dj + 3) <= 6u);
            const float rel = sqrtf((float)(di * di + dj * dj));
            const float mk = sigm((wd[r] - rel) * sh[r]);
            float s = sc[tl][r] * 0.125f - (1.f - mk) * 10000.f;
            s = win ? s : -3e38f;
            sc[tl][r] = s;
            mx[r] = fmaxf(mx[r], s);
        }
    }
#pragma unroll
    for (int r = 0; r < 4; ++r) {
        mx[r] = fmaxf(mx[r], __shfl_xor(mx[r], 1));
        mx[r] = fmaxf(mx[r], __shfl_xor(mx[r], 2));
        mx[r] = fmaxf(mx[r], __shfl_xor(mx[r], 4));
        mx[r] = fmaxf(mx[r], __shfl_xor(mx[r], 8));
    }
    float sm[4] = {0.f, 0.f, 0.f, 0.f};
#pragma unroll
    for (int tl = 0; tl < 8; ++tl)
#pragma unroll
        for (int r = 0; r < 4; ++r) {
            const float e = __expf(sc[tl][r] - mx[r]);
            sc[tl][r] = e; sm[r] += e;
        }
#pragma unroll
    for (int r = 0; r < 4; ++r) {
        sm[r] += __shfl_xor(sm[r], 1);
        sm[r] += __shfl_xor(sm[r], 2);
        sm[r] += __shfl_xor(sm[r], 4);
        sm[r] += __shfl_xor(sm[r], 8);
        sm[r] = 1.f / sm[r];
    }

    __syncthreads();   // Ksh frag reads done before P overwrites
#pragma unroll
    for (int tl = 0; tl < 8; ++tl)
#pragma unroll
        for (int r = 0; r < 4; ++r) {
            __half pv = __float2half(sc[tl][r] * sm[r]);
            Psh[((wave << 4) + (fq << 2) + r) * PT + ((t0 + tl) << 4) + fr] = *(short*)&pv;
        }
    __syncthreads();

    // ---- PV: K = 128 (4x32), windowed at t0*16 ----
    f32x4 o[4] = {};
    const int pra = (wave << 4) + fr;
    const int cb = t0 << 4;
#pragma unroll
    for (int s = 0; s < 4; ++s) {
        half8 pa = *(const half8*)&Psh[pra * PT + cb + (fq << 3) + (s << 5)];
#pragma unroll
        for (int dt = 0; dt < 4; ++dt) {
            half8 vbf = *(const half8*)&Vt[((dt << 4) + fr) * PT + cb + (fq << 3) + (s << 5)];
            o[dt] = __builtin_amdgcn_mfma_f32_16x16x32_f16(pa, vbf, o[dt], 0, 0, 0);
        }
    }

#pragma unroll
    for (int r = 0; r < 4; ++r) {
        float ss = o[0][r]*o[0][r] + o[1][r]*o[1][r] + o[2][r]*o[2][r] + o[3][r]*o[3][r];
        ss += __shfl_xor(ss, 1); ss += __shfl_xor(ss, 2);
        ss += __shfl_xor(ss, 4); ss += __shfl_xor(ss, 8);
        const size_t rowb = (((size_t)(b << 12) + lq[r]) << 8) + h * 64;
#pragma unroll
        for (int dt = 0; dt < 4; ++dt)
            attn_o[rowb + (dt << 4) + fr] = o[dt][r];
        if (fr == 0) sumsq4[(((b << 12) + lq[r]) << 2) + h] = ss;
    }
}

extern "C" void kernel_launch(void* const* d_in, const int* in_sizes, int n_in,
                              void* d_out, int out_size, void* d_ws, size_t ws_size,
                              hipStream_t stream)
{
    const float* x      = (const float*)d_in[0];
    const float* W_qkv  = (const float*)d_in[1];
    const float* w_qn   = (const float*)d_in[2];
    const float* w_kn   = (const float*)d_in[3];
    const float* W_wp   = (const float*)d_in[4];
    const float* b_wp   = (const float*)d_in[5];
    const float* w_on   = (const float*)d_in[6];
    const float* W_out  = (const float*)d_in[7];
    const float* W_gate = (const float*)d_in[8];
    const float* b_gate = (const float*)d_in[9];
    float* out = (float*)d_out;

    __half* ws16 = (__half*)d_ws;
    __half* xh  = ws16;                    // [8][8192][32]
    __half* wqh = xh  + 2097152;           // [8][768][32]
    __half* wql = wqh + 196608;
    __half* wgh = wql + 196608;            // [8][256][32]
    __half* wgl = wgh + 65536;
    __half* woh = wgl + 65536;
    __half* wol = woh + 65536;
    __half* qhp = wol + 65536;             // [8192][256]
    __half* khp = qhp + 2097152;
    __half* vhp = khp + 2097152;
    __half* mh  = vhp + 2097152;
    float* attn_o = (float*)(mh + 2097152);  // [8192][256] f32
    float* widthp = attn_o + 2097152;
    float* sharpp = widthp + 32768;
    float* sumsq4 = sharpp + 32768;

    // x -> f16 blocked + wp; weights -> transposed f16 hi/lo blocked
    prep_kernel<<<304, 256, 0, stream>>>(x, W_qkv, W_gate, W_out, W_wp, b_wp,
                                         xh, wqh, wql, wgh, wgl, woh, wol,
                                         widthp, sharpp);
    // qkv GEMM (zero-LDS reg pipeline) + fused silu/rmsnorm/rope
    gemm_qkv<<<dim3(6, 128), 256, 0, stream>>>(xh, wqh, wql, w_qn, w_kn,
                                               qhp, khp, vhp);
    // patch-GEMM local attention (raw O + sumsq)
    attn_mfma<<<dim3(64, 4, 2), 256, 0, stream>>>(qhp, khp, vhp, widthp, sharpp,
                                                  attn_o, sumsq4);
    // gate gemm (zero-LDS) + fused o-rmsnorm + merge -> merged f16
    gemm_gate<<<dim3(4, 128), 256, 0, stream>>>(vhp, wgh, wgl, b_gate,
                                                attn_o, sumsq4, w_on, mh);
    // final silu(merged @ W_out) (zero-LDS)
    gemm_out<<<dim3(4, 128), 256, 0, stream>>>(mh, woh, wol, out);
}

// Round 8
// 132.782 us; speedup vs baseline: 1.1220x; 1.1220x over previous
//
#include <hip/hip_runtime.h>
#include <hip/hip_fp16.h>
#include <math.h>

__device__ __forceinline__ float sigm(float x)  { return 1.0f / (1.0f + __expf(-x)); }
__device__ __forceinline__ float siluf(float x) { return x * sigm(x); }

typedef _Float16 half8  __attribute__((ext_vector_type(8)));
typedef _Float16 half4  __attribute__((ext_vector_type(4)));
typedef float    f32x4  __attribute__((ext_vector_type(4)));

// async global->LDS, 16 B/lane: LDS dest = wave-uniform base + lane*16 (packed!)
__device__ __forceinline__ void gld16(const void* g, void* l) {
    __builtin_amdgcn_global_load_lds(
        (const __attribute__((address_space(1))) unsigned*)g,
        (__attribute__((address_space(3))) unsigned*)l, 16, 0, 0);
}

template <int N>
__device__ __forceinline__ void wait_vmcnt() {
    if constexpr (N == 0)      asm volatile("s_waitcnt vmcnt(0)" ::: "memory");
    else if constexpr (N == 3) asm volatile("s_waitcnt vmcnt(3)" ::: "memory");
    else if constexpr (N == 5) asm volatile("s_waitcnt vmcnt(5)" ::: "memory");
    else if constexpr (N == 6) asm volatile("s_waitcnt vmcnt(6)" ::: "memory");
}

// =======================================================================
// 2-term split GEMM core (T3+T4 counted-vmcnt, dbuf).  R16: per-block
// k-order STAGGER (kc = (kb+koff)&7).  128 m-blocks share each B panel;
// un-staggered they read the same lines in lockstep -> same-line L2 bank
// serialization (no multicast).  Staggering spreads the 128 readers over
// all 8 k-slices.  k-sum is order-independent (f32 reorder ~1e-6 rel).
// =======================================================================
template <int MI, int AMODE>
__device__ __forceinline__ void gemm_core16(
    const __half* __restrict__ A16,
    const __half* __restrict__ Bhi, const __half* __restrict__ Blo,
    int nbs, int m0, int n0, int t, int koff, f32x4 (&acc)[MI][4])
{
    __shared__ short As[2][MI * 1024], BsHi[2][4096], BsLo[2][4096];
    const int lane = t & 63, wave = t >> 6;
    const int wm = (wave >> 1) * (MI << 4), wn = (wave & 1) << 6;
    const int fr = lane & 15, fq = lane >> 4;
    constexpr int NL = MI / 2 + 4;         // gld16s per wave per stage

    auto stage = [&](int kb, int buf) {
        const int kc = (kb + koff) & 7;    // staggered k-slice
#pragma unroll
        for (int hf = 0; hf < MI / 2; ++hf) {          // A: MI*8 rows/wave
            const int rr = wave * (MI << 3) + (hf << 4);
            size_t ga;
            if (AMODE == 0)
                ga = (((size_t)(kc * 8192 + m0 + rr)) << 5) + (lane << 3);
            else
                ga = (((size_t)(m0 + rr + (lane >> 2))) << 8) + (kc << 5) + ((lane & 3) << 3);
            gld16(A16 + ga, &As[buf][rr << 5]);
        }
#pragma unroll
        for (int hf = 0; hf < 2; ++hf) {               // B: 32 rows/wave
            const int rr = (wave << 5) + (hf << 4);
            const size_t gb = (((size_t)(kc * nbs + n0 + rr)) << 5) + (lane << 3);
            gld16(Bhi + gb, &BsHi[buf][rr << 5]);
            gld16(Blo + gb, &BsLo[buf][rr << 5]);
        }
    };

    stage(0, 0);
#pragma unroll
    for (int kb = 0; kb < 8; ++kb) {
        const int cur = kb & 1;
        if (kb < 7) {
            stage(kb + 1, cur ^ 1);        // NL loads now in flight
            wait_vmcnt<NL>();              // tile-k loads complete
        } else {
            wait_vmcnt<0>();
        }
        __builtin_amdgcn_s_barrier();      // all waves' tile-k writes visible

        half8 a[MI], bh[4], bl[4];
#pragma unroll
        for (int i = 0; i < MI; ++i)
            a[i] = *(const half8*)&As[cur][((wm + (i << 4) + fr) << 5) + (fq << 3)];
#pragma unroll
        for (int i = 0; i < 4; ++i) {
            const int boff = ((wn + (i << 4) + fr) << 5) + (fq << 3);
            bh[i] = *(const half8*)&BsHi[cur][boff];
            bl[i] = *(const half8*)&BsLo[cur][boff];
        }
#pragma unroll
        for (int mi = 0; mi < MI; ++mi)
#pragma unroll
            for (int ni = 0; ni < 4; ++ni) {
                acc[mi][ni] = __builtin_amdgcn_mfma_f32_16x16x32_f16(a[mi], bh[ni], acc[mi][ni], 0, 0, 0);
                acc[mi][ni] = __builtin_amdgcn_mfma_f32_16x16x32_f16(a[mi], bl[ni], acc[mi][ni], 0, 0, 0);
            }

        if (kb < 7) __builtin_amdgcn_s_barrier();
    }
}

// =======================================================================
// 64x64-tile core, 4 waves all in m; counted-vmcnt; R16 k-stagger.
// AMODE 1 (A row-major [m][256]).  Used by gate/out at 512 blocks.
// =======================================================================
__device__ __forceinline__ void gemm_core64(
    const __half* __restrict__ A16,
    const __half* __restrict__ Bhi, const __half* __restrict__ Blo,
    int m0, int n0, int t, int koff, f32x4 (&acc)[4])
{
    __shared__ short As[2][2048], BsHi[2][2048], BsLo[2][2048];
    const int lane = t & 63, wave = t >> 6;
    const int wm = wave << 4;
    const int fr = lane & 15, fq = lane >> 4;

    auto stage = [&](int kb, int buf) {
        const int kc = (kb + koff) & 7;
        const int rr = wave << 4;          // 16 rows/wave (A and B)
        const size_t ga = (((size_t)(m0 + rr + (lane >> 2))) << 8) + (kc << 5) + ((lane & 3) << 3);
        gld16(A16 + ga, &As[buf][rr << 5]);
        const size_t gb = (((size_t)(kc * 256 + n0 + rr)) << 5) + (lane << 3);
        gld16(Bhi + gb, &BsHi[buf][rr << 5]);
        gld16(Blo + gb, &BsLo[buf][rr << 5]);
    };

    stage(0, 0);
#pragma unroll
    for (int kb = 0; kb < 8; ++kb) {
        const int cur = kb & 1;
        if (kb < 7) {
            stage(kb + 1, cur ^ 1);
            wait_vmcnt<3>();
        } else {
            wait_vmcnt<0>();
        }
        __builtin_amdgcn_s_barrier();

        half8 a = *(const half8*)&As[cur][((wm + fr) << 5) + (fq << 3)];
        half8 bh[4], bl[4];
#pragma unroll
        for (int ni = 0; ni < 4; ++ni) {
            const int boff = (((ni << 4) + fr) << 5) + (fq << 3);
            bh[ni] = *(const half8*)&BsHi[cur][boff];
            bl[ni] = *(const half8*)&BsLo[cur][boff];
        }
#pragma unroll
        for (int ni = 0; ni < 4; ++ni) {
            acc[ni] = __builtin_amdgcn_mfma_f32_16x16x32_f16(a, bh[ni], acc[ni], 0, 0, 0);
            acc[ni] = __builtin_amdgcn_mfma_f32_16x16x32_f16(a, bl[ni], acc[ni], 0, 0, 0);
        }

        if (kb < 7) __builtin_amdgcn_s_barrier();
    }
}

// =======================================================================
// Prep (R4 form): x -> f16 k-blocked + wp; weights -> [kb][n][32] hi/lo.
// =======================================================================
__global__ __launch_bounds__(256) void prep_kernel(
    const float* __restrict__ x, const float* __restrict__ Wqkv,
    const float* __restrict__ Wgate, const float* __restrict__ Wout,
    const float* __restrict__ Wwp, const float* __restrict__ bwp,
    __half* __restrict__ xh,
    __half* __restrict__ wqh, __half* __restrict__ wql,
    __half* __restrict__ wgh, __half* __restrict__ wgl,
    __half* __restrict__ woh, __half* __restrict__ wol,
    float* __restrict__ width, float* __restrict__ sharp)
{
    __shared__ float xs[32][260];
    const int t = threadIdx.x;
    const int blk = blockIdx.x;
    if (blk < 256) {
        const int row0 = blk << 5;
        for (int e = t; e < 2048; e += 256) {
            int r = e >> 6, cc = (e & 63) << 2;
            *(float4*)&xs[r][cc] = *(const float4*)&x[(size_t)(row0 + r) * 256 + cc];
        }
        __syncthreads();
        const int r = t >> 3, kb = t & 7;
        __half hibuf[32];
#pragma unroll
        for (int i = 0; i < 32; ++i)
            hibuf[i] = __float2half(xs[r][(kb << 5) + i]);
        const size_t ob = ((size_t)(kb * 8192 + row0 + r)) << 5;
#pragma unroll
        for (int i = 0; i < 4; ++i)
            *(int4*)&xh[ob + (i << 3)] = *(int4*)&hibuf[i << 3];
        // wp: thread (r, n=kb); 4 accumulators break the 256-FMA dep chain
        float a0 = 0.f, a1 = 0.f, a2 = 0.f, a3 = 0.f;
#pragma unroll 4
        for (int k = 0; k < 256; k += 4) {
            a0 += xs[r][k + 0] * Wwp[(k + 0) * 8 + kb];
            a1 += xs[r][k + 1] * Wwp[(k + 1) * 8 + kb];
            a2 += xs[r][k + 2] * Wwp[(k + 2) * 8 + kb];
            a3 += xs[r][k + 3] * Wwp[(k + 3) * 8 + kb];
        }
        const float acc = (a0 + a1) + (a2 + a3);
        float s = sigm(siluf(acc + bwp[kb]));
        const int row = row0 + r;
        if (kb < 4) width[row * 4 + kb] = s * 4.242640687119285f + 0.5f;  // sqrt(18)
        else        sharp[row * 4 + kb - 4] = s * 9.5f + 0.5f;
    } else {
        const float* W; __half *Whi, *Wlo; int N, nb0, ncnt;
        if (blk < 288)      { W = Wqkv;  Whi = wqh; Wlo = wql; N = 768; nb0 = (blk - 256) * 24; ncnt = 24; }
        else if (blk < 296) { W = Wgate; Whi = wgh; Wlo = wgl; N = 256; nb0 = (blk - 288) * 32; ncnt = 32; }
        else                { W = Wout;  Whi = woh; Wlo = wol; N = 256; nb0 = (blk - 296) * 32; ncnt = 32; }
        for (int j = 0; j < ncnt; ++j)
            xs[j][t] = W[(size_t)t * N + nb0 + j];   // t = k row
        __syncthreads();
        for (int c = t; c < ncnt * 8; c += 256) {
            const int j = c >> 3, kb = c & 7;
            __half hibuf[32], lobuf[32];
#pragma unroll
            for (int i = 0; i < 32; ++i) {
                float v = xs[j][(kb << 5) + i];
                __half hv = __float2half(v);
                hibuf[i] = hv;
                lobuf[i] = __float2half(v - __half2float(hv));
            }
            const size_t ob = ((size_t)(kb * N + nb0 + j)) << 5;
#pragma unroll
            for (int i = 0; i < 4; ++i) {
                *(int4*)&Whi[ob + (i << 3)] = *(int4*)&hibuf[i << 3];
                *(int4*)&Wlo[ob + (i << 3)] = *(int4*)&lobuf[i << 3];
            }
        }
    }
}

// =======================================================================
// qkv GEMM (64x128 tiles, 768 blocks = 3/CU, k-staggered) + fused silu ->
// rmsnorm -> RoPE(pos=head) -> f16 stores.
// =======================================================================
__global__ __launch_bounds__(256, 3) void gemm_qkv(
    const __half* __restrict__ xh,
    const __half* __restrict__ wqh, const __half* __restrict__ wql,
    const float* __restrict__ wq, const float* __restrict__ wk,
    __half* __restrict__ qh, __half* __restrict__ kh, __half* __restrict__ vh)
{
    const int t  = threadIdx.x;
    const int m0 = blockIdx.y << 6, n0 = blockIdx.x << 7;
    f32x4 acc[2][4] = {};
    gemm_core16<2, 0>(xh, wqh, wql, 768, m0, n0, t, blockIdx.y & 7, acc);

    const int lane = t & 63, wave = t >> 6;
    const int wm = (wave >> 1) << 5, wn = (wave & 1) << 6;
    const int fr = lane & 15, fq = lane >> 4;
    const int gc0 = n0 + wn;
    const int seg = gc0 >> 8;          // 0=q, 1=k, 2=v
    const int h   = (gc0 >> 6) & 3;
    const int hc0 = h << 6;

#pragma unroll
    for (int mi = 0; mi < 2; ++mi)
#pragma unroll
        for (int ni = 0; ni < 4; ++ni)
#pragma unroll
            for (int r = 0; r < 4; ++r)
                acc[mi][ni][r] = siluf(acc[mi][ni][r]);

    if (seg == 2) {
#pragma unroll
        for (int mi = 0; mi < 2; ++mi)
#pragma unroll
            for (int r = 0; r < 4; ++r) {
                const size_t row = m0 + wm + (mi << 4) + (fq << 2) + r;
#pragma unroll
                for (int ni = 0; ni < 4; ++ni)
                    vh[row * 256 + hc0 + (ni << 4) + fr] = __float2half(acc[mi][ni][r]);
            }
    } else {
        const float* wnorm = seg ? wk : wq;
        float wv[4];
#pragma unroll
        for (int ni = 0; ni < 4; ++ni) wv[ni] = wnorm[(ni << 4) + fr];
        float cs[2], sn[2];
#pragma unroll
        for (int j = 0; j < 2; ++j) {
            const int d = (j << 4) + fr;
            const float freq = powf(10000.f, -(float)d * (1.f / 32.f));
            const float ang = (float)h * freq;    // pos = arange(H) reference quirk
            cs[j] = cosf(ang); sn[j] = sinf(ang);
        }
        __half* dstbase = (seg ? kh : qh);
#pragma unroll
        for (int mi = 0; mi < 2; ++mi)
#pragma unroll
            for (int r = 0; r < 4; ++r) {
                float ss = acc[mi][0][r] * acc[mi][0][r] + acc[mi][1][r] * acc[mi][1][r]
                         + acc[mi][2][r] * acc[mi][2][r] + acc[mi][3][r] * acc[mi][3][r];
                ss += __shfl_xor(ss, 1); ss += __shfl_xor(ss, 2);
                ss += __shfl_xor(ss, 4); ss += __shfl_xor(ss, 8);
                const float rinv = 1.f / sqrtf(ss * (1.f / 64.f) + 1e-6f);
                float xv[4];
#pragma unroll
                for (int ni = 0; ni < 4; ++ni) xv[ni] = acc[mi][ni][r] * rinv * wv[ni];
                const float o0 = xv[0] * cs[0] - xv[2] * sn[0];
                const float o2 = xv[0] * sn[0] + xv[2] * cs[0];
                const float o1 = xv[1] * cs[1] - xv[3] * sn[1];
                const float o3 = xv[1] * sn[1] + xv[3] * cs[1];
                const size_t row = m0 + wm + (mi << 4) + (fq << 2) + r;
                __half* dst = dstbase + row * 256 + hc0;
                dst[fr]      = __float2half(o0);
                dst[16 + fr] = __float2half(o1);
                dst[32 + fr] = __float2half(o2);
                dst[48 + fr] = __float2half(o3);
            }
    }
}

// ---- gate GEMM (64x64 tiles, 512 blocks, k-staggered) + o-rmsnorm + merge ----
__global__ __launch_bounds__(256, 2) void gemm_gate(
    const __half* __restrict__ vh,
    const __half* __restrict__ wgh, const __half* __restrict__ wgl,
    const float* __restrict__ bias, const float* __restrict__ attn_o,
    const float* __restrict__ sumsq4, const float* __restrict__ w_onorm,
    __half* __restrict__ mh)
{
    const int t  = threadIdx.x;
    const int m0 = blockIdx.y << 6, n0 = blockIdx.x << 6;
    f32x4 acc[4] = {};
    gemm_core64(vh, wgh, wgl, m0, n0, t, blockIdx.y & 7, acc);

    const int lane = t & 63, wave = t >> 6;
    const int wm = wave << 4;
    const int fr = lane & 15, fq = lane >> 4;

    float rmsf[4];
#pragma unroll
    for (int r = 0; r < 4; ++r) {
        const int m = m0 + wm + (fq << 2) + r;
        float4 s4 = *(const float4*)&sumsq4[(size_t)m * 4];
        rmsf[r] = 1.f / sqrtf((s4.x + s4.y + s4.z + s4.w) * (1.f / 256.f) + 1e-6f);
    }

#pragma unroll
    for (int ni = 0; ni < 4; ++ni) {
        const int n  = n0 + (ni << 4) + fr;
        const int mb = m0 + wm + (fq << 2);
        const float bb  = bias[n];
        const float won = w_onorm[n];
#pragma unroll
        for (int r = 0; r < 4; ++r) {
            const int m = mb + r;
            const float g  = sigm(siluf(acc[ni][r] + bb));
            const float vv = __half2float(vh[(size_t)m * 256 + n]);
            const float oo = attn_o[(size_t)m * 256 + n] * rmsf[r] * won;
            mh[(size_t)m * 256 + n] = __float2half(g * vv + (1.f - g) * oo);
        }
    }
}

// ---- final GEMM (64x64 tiles, 512 blocks, k-staggered): out = silu(mh @ W_out) ----
__global__ __launch_bounds__(256, 2) void gemm_out(
    const __half* __restrict__ mh,
    const __half* __restrict__ woh, const __half* __restrict__ wol,
    float* __restrict__ out)
{
    const int t  = threadIdx.x;
    const int m0 = blockIdx.y << 6, n0 = blockIdx.x << 6;
    f32x4 acc[4] = {};
    gemm_core64(mh, woh, wol, m0, n0, t, blockIdx.y & 7, acc);

    const int lane = t & 63, wave = t >> 6;
    const int wm = wave << 4;
    const int fr = lane & 15, fq = lane >> 4;
#pragma unroll
    for (int ni = 0; ni < 4; ++ni) {
        const int n  = n0 + (ni << 4) + fr;
        const int mb = m0 + wm + (fq << 2);
#pragma unroll
        for (int r = 0; r < 4; ++r)
            out[(size_t)(mb + r) * 256 + n] = siluf(acc[ni][r]);
    }
}

// =======================================================================
// Patch-GEMM local attention (R1 version: Ksh-staged, windowed n-tiles).
// =======================================================================
#define PT 216   // P / Vt row stride (halves)

__global__ __launch_bounds__(256, 2) void attn_mfma(
    const __half* __restrict__ qh, const __half* __restrict__ kh,
    const __half* __restrict__ vh, const float* __restrict__ width,
    const float* __restrict__ sharp, float* __restrict__ attn_o,
    float* __restrict__ sumsq4)
{
    __shared__ short smem[27648];          // 55296 B
    short* Ksh = smem;                     // [208][64] chunk-swizzled; overlaid by P [64][PT]
    short* Psh = smem;
    short* Vt  = smem + 13824;             // [64 d][PT]

    const int t = threadIdx.x;
    const int lane = t & 63, wave = t >> 6;
    const int fr = lane & 15, fq = lane >> 4;
    const int patch = blockIdx.x, h = blockIdx.y, b = blockIdx.z;
    const int pr0 = (patch >> 3) << 3, pc0 = (patch & 7) << 3;
    const int t0 = (wave * 28) >> 4;       // first n-tile of this wave's window

    float wd[4], sh[4]; int lq[4];
#pragma unroll
    for (int r = 0; r < 4; ++r) {
        const int q = (wave << 4) + (fq << 2) + r;
        lq[r] = (pr0 + (q >> 3)) * 64 + pc0 + (q & 7);
        wd[r] = width[((b << 12) + lq[r]) * 4 + h];
        sh[r] = sharp[((b << 12) + lq[r]) * 4 + h];
    }

    // ---- Q straight into A-frags ----
    const int qrow = (wave << 4) + fr;
    const int lqr = (pr0 + (qrow >> 3)) * 64 + pc0 + (qrow & 7);
    const __half* qptr = qh + (((size_t)(b << 12) + lqr) << 8) + (h << 6) + (fq << 3);
    half8 a0 = *(const half8*)qptr;
    half8 a1 = *(const half8*)(qptr + 32);

    // ---- K/V staging (clamped+select, single drain) ----
    const int srow = t >> 5;
    const int d2 = (t & 31) << 1;
    const size_t cbase = (((size_t)b << 12) * 256) + (size_t)h * 64 + d2;

    unsigned kb[25], vb[25];
#pragma unroll
    for (int p5 = 0; p5 < 25; ++p5) {
        const int prow = p5 * 8 + srow;
        const int pi = prow / 14, pj = prow - pi * 14;
        const int gr = pr0 - 3 + pi, gc = pc0 - 3 + pj;
        const bool ok = (prow < 196) & ((unsigned)gr < 64u) & ((unsigned)gc < 64u);
        const int grc = min(max(gr, 0), 63), gcc = min(max(gc, 0), 63);
        const size_t off = cbase + (size_t)(grc * 64 + gcc) * 256;
        unsigned kv = *(const unsigned*)(kh + off);
        unsigned vv = *(const unsigned*)(vh + off);
        kb[p5] = ok ? kv : 0u;
        vb[p5] = ok ? vv : 0u;
    }

    const int chunk = d2 >> 3, dlo = d2 & 7;
#pragma unroll
    for (int p5 = 0; p5 < 25; ++p5) {
        const int prow = p5 * 8 + srow;
        *(unsigned*)&Ksh[(prow << 6) + ((chunk ^ (prow & 7)) << 3) + dlo] = kb[p5];
        Vt[(d2)     * PT + prow] = (short)(vb[p5] & 0xffffu);
        Vt[(d2 + 1) * PT + prow] = (short)(vb[p5] >> 16);
    }
    // zero Ksh rows 200..207 (read by QK tile 12; never staged)
    if (t < 128) {
        const int rr = 200 + (t >> 4);
        *(unsigned*)&Ksh[(rr << 6) + (((t & 15) ^ ((rr & 7) << 1)) << 2)] = 0u;
    }
    // zero Vt pad cols 196..215
    for (int i = t; i < 64 * 20; i += 256)
        Vt[(i / 20) * PT + 196 + (i % 20)] = 0;
    __syncthreads();

    // ---- QK^T: 8 windowed n-tiles of 16 positions ----
    f32x4 sc[8];
#pragma unroll
    for (int tl = 0; tl < 8; ++tl) {
        const int kr = ((t0 + tl) << 4) + fr;
        half8 b0 = *(const half8*)&Ksh[(kr << 6) + (((0 + fq) ^ (kr & 7)) << 3)];
        half8 b1 = *(const half8*)&Ksh[(kr << 6) + (((4 + fq) ^ (kr & 7)) << 3)];
        f32x4 z = {0.f, 0.f, 0.f, 0.f};
        z = __builtin_amdgcn_mfma_f32_16x16x32_f16(a0, b0, z, 0, 0, 0);
        sc[tl] = __builtin_amdgcn_mfma_f32_16x16x32_f16(a1, b1, z, 0, 0, 0);
    }

    // ---- mask + softmax ----
    float mx[4] = {-3e38f, -3e38f, -3e38f, -3e38f};
#pragma unroll
    for (int tl = 0; tl < 8; ++tl) {
        const int p = ((t0 + tl) << 4) + fr;
        const int pi = p / 14, pj = p - pi * 14;
        const bool pvld = p < 196;
#pragma unroll
        for (int r = 0; r < 4; ++r) {
            const int q = (wave << 4) + (fq << 2) + r;
            const int di = pi - 3 - ((q >> 3) & 7), dj = pj - 3 - (q & 7);
            const bool win = pvld & ((unsigned)(di + 3) <= 6u) & ((unsigned)(dj + 3) <= 6u);
            const float rel = sqrtf((float)(di * di + dj * dj));
            const float mk = sigm((wd[r] - rel) * sh[r]);
            float s = sc[tl][r] * 0.125f - (1.f - mk) * 10000.f;
            s = win ? s : -3e38f;
            sc[tl][r] = s;
            mx[r] = fmaxf(mx[r], s);
        }
    }
#pragma unroll
    for (int r = 0; r < 4; ++r) {
        mx[r] = fmaxf(mx[r], __shfl_xor(mx[r], 1));
        mx[r] = fmaxf(mx[r], __shfl_xor(mx[r], 2));
        mx[r] = fmaxf(mx[r], __shfl_xor(mx[r], 4));
        mx[r] = fmaxf(mx[r], __shfl_xor(mx[r], 8));
    }
    float sm[4] = {0.f, 0.f, 0.f, 0.f};
#pragma unroll
    for (int tl = 0; tl < 8; ++tl)
#pragma unroll
        for (int r = 0; r < 4; ++r) {
            const float e = __expf(sc[tl][r] - mx[r]);
            sc[tl][r] = e; sm[r] += e;
        }
#pragma unroll
    for (int r = 0; r < 4; ++r) {
        sm[r] += __shfl_xor(sm[r], 1);
        sm[r] += __shfl_xor(sm[r], 2);
        sm[r] += __shfl_xor(sm[r], 4);
        sm[r] += __shfl_xor(sm[r], 8);
        sm[r] = 1.f / sm[r];
    }

    __syncthreads();   // Ksh frag reads done before P overwrites
#pragma unroll
    for (int tl = 0; tl < 8; ++tl)
#pragma unroll
        for (int r = 0; r < 4; ++r) {
            __half pv = __float2half(sc[tl][r] * sm[r]);
            Psh[((wave << 4) + (fq << 2) + r) * PT + ((t0 + tl) << 4) + fr] = *(short*)&pv;
        }
    __syncthreads();

    // ---- PV: K = 128 (4x32), windowed at t0*16 ----
    f32x4 o[4] = {};
    const int pra = (wave << 4) + fr;
    const int cb = t0 << 4;
#pragma unroll
    for (int s = 0; s < 4; ++s) {
        half8 pa = *(const half8*)&Psh[pra * PT + cb + (fq << 3) + (s << 5)];
#pragma unroll
        for (int dt = 0; dt < 4; ++dt) {
            half8 vbf = *(const half8*)&Vt[((dt << 4) + fr) * PT + cb + (fq << 3) + (s << 5)];
            o[dt] = __builtin_amdgcn_mfma_f32_16x16x32_f16(pa, vbf, o[dt], 0, 0, 0);
        }
    }

#pragma unroll
    for (int r = 0; r < 4; ++r) {
        float ss = o[0][r]*o[0][r] + o[1][r]*o[1][r] + o[2][r]*o[2][r] + o[3][r]*o[3][r];
        ss += __shfl_xor(ss, 1); ss += __shfl_xor(ss, 2);
        ss += __shfl_xor(ss, 4); ss += __shfl_xor(ss, 8);
        const size_t rowb = (((size_t)(b << 12) + lq[r]) << 8) + h * 64;
#pragma unroll
        for (int dt = 0; dt < 4; ++dt)
            attn_o[rowb + (dt << 4) + fr] = o[dt][r];
        if (fr == 0) sumsq4[(((b << 12) + lq[r]) << 2) + h] = ss;
    }
}

extern "C" void kernel_launch(void* const* d_in, const int* in_sizes, int n_in,
                              void* d_out, int out_size, void* d_ws, size_t ws_size,
                              hipStream_t stream)
{
    const float* x      = (const float*)d_in[0];
    const float* W_qkv  = (const float*)d_in[1];
    const float* w_qn   = (const float*)d_in[2];
    const float* w_kn   = (const float*)d_in[3];
    const float* W_wp   = (const float*)d_in[4];
    const float* b_wp   = (const float*)d_in[5];
    const float* w_on   = (const float*)d_in[6];
    const float* W_out  = (const float*)d_in[7];
    const float* W_gate = (const float*)d_in[8];
    const float* b_gate = (const float*)d_in[9];
    float* out = (float*)d_out;

    __half* ws16 = (__half*)d_ws;
    __half* xh  = ws16;                    // [8][8192][32]
    __half* wqh = xh  + 2097152;           // [8][768][32]
    __half* wql = wqh + 196608;
    __half* wgh = wql + 196608;            // [8][256][32]
    __half* wgl = wgh + 65536;
    __half* woh = wgl + 65536;
    __half* wol = woh + 65536;
    __half* qhp = wol + 65536;             // [8192][256]
    __half* khp = qhp + 2097152;
    __half* vhp = khp + 2097152;
    __half* mh  = vhp + 2097152;
    float* attn_o = (float*)(mh + 2097152);  // [8192][256] f32
    float* widthp = attn_o + 2097152;
    float* sharpp = widthp + 32768;
    float* sumsq4 = sharpp + 32768;

    // x -> f16 blocked + wp; weights -> transposed f16 hi/lo blocked
    prep_kernel<<<304, 256, 0, stream>>>(x, W_qkv, W_gate, W_out, W_wp, b_wp,
                                         xh, wqh, wql, wgh, wgl, woh, wol,
                                         widthp, sharpp);
    // qkv GEMM (2-term, pipelined, k-staggered) + fused silu/rmsnorm/rope
    gemm_qkv<<<dim3(6, 128), 256, 0, stream>>>(xh, wqh, wql, w_qn, w_kn,
                                               qhp, khp, vhp);
    // patch-GEMM local attention (raw O + sumsq)
    attn_mfma<<<dim3(64, 4, 2), 256, 0, stream>>>(qhp, khp, vhp, widthp, sharpp,
                                                  attn_o, sumsq4);
    // gate gemm (64x64, 512 blocks, k-staggered) + fused o-rmsnorm + merge
    gemm_gate<<<dim3(4, 128), 256, 0, stream>>>(vhp, wgh, wgl, b_gate,
                                                attn_o, sumsq4, w_on, mh);
    // final silu(merged @ W_out) (64x64, 512 blocks, k-staggered)
    gemm_out<<<dim3(4, 128), 256, 0, stream>>>(mh, woh, wol, out);
}

// Round 9
// 132.550 us; speedup vs baseline: 1.1239x; 1.0017x over previous
//
#include <hip/hip_runtime.h>
#include <hip/hip_fp16.h>
#include <math.h>

__device__ __forceinline__ float sigm(float x)  { return 1.0f / (1.0f + __expf(-x)); }
__device__ __forceinline__ float siluf(float x) { return x * sigm(x); }

typedef _Float16 half8  __attribute__((ext_vector_type(8)));
typedef _Float16 half4  __attribute__((ext_vector_type(4)));
typedef float    f32x4  __attribute__((ext_vector_type(4)));
typedef unsigned u32x2  __attribute__((ext_vector_type(2)));

// async global->LDS, 16 B/lane: LDS dest = wave-uniform base + lane*16 (packed!)
__device__ __forceinline__ void gld16(const void* g, void* l) {
    __builtin_amdgcn_global_load_lds(
        (const __attribute__((address_space(1))) unsigned*)g,
        (__attribute__((address_space(3))) unsigned*)l, 16, 0, 0);
}

template <int N>
__device__ __forceinline__ void wait_vmcnt() {
    if constexpr (N == 0)      asm volatile("s_waitcnt vmcnt(0)" ::: "memory");
    else if constexpr (N == 3) asm volatile("s_waitcnt vmcnt(3)" ::: "memory");
    else if constexpr (N == 5) asm volatile("s_waitcnt vmcnt(5)" ::: "memory");
    else if constexpr (N == 6) asm volatile("s_waitcnt vmcnt(6)" ::: "memory");
}

// =======================================================================
// 2-term split GEMM core (T3+T4 counted-vmcnt, dbuf, R16 k-stagger).
// =======================================================================
template <int MI, int AMODE>
__device__ __forceinline__ void gemm_core16(
    const __half* __restrict__ A16,
    const __half* __restrict__ Bhi, const __half* __restrict__ Blo,
    int nbs, int m0, int n0, int t, int koff, f32x4 (&acc)[MI][4])
{
    __shared__ short As[2][MI * 1024], BsHi[2][4096], BsLo[2][4096];
    const int lane = t & 63, wave = t >> 6;
    const int wm = (wave >> 1) * (MI << 4), wn = (wave & 1) << 6;
    const int fr = lane & 15, fq = lane >> 4;
    constexpr int NL = MI / 2 + 4;         // gld16s per wave per stage

    auto stage = [&](int kb, int buf) {
        const int kc = (kb + koff) & 7;    // staggered k-slice
#pragma unroll
        for (int hf = 0; hf < MI / 2; ++hf) {          // A: MI*8 rows/wave
            const int rr = wave * (MI << 3) + (hf << 4);
            size_t ga;
            if (AMODE == 0)
                ga = (((size_t)(kc * 8192 + m0 + rr)) << 5) + (lane << 3);
            else
                ga = (((size_t)(m0 + rr + (lane >> 2))) << 8) + (kc << 5) + ((lane & 3) << 3);
            gld16(A16 + ga, &As[buf][rr << 5]);
        }
#pragma unroll
        for (int hf = 0; hf < 2; ++hf) {               // B: 32 rows/wave
            const int rr = (wave << 5) + (hf << 4);
            const size_t gb = (((size_t)(kc * nbs + n0 + rr)) << 5) + (lane << 3);
            gld16(Bhi + gb, &BsHi[buf][rr << 5]);
            gld16(Blo + gb, &BsLo[buf][rr << 5]);
        }
    };

    stage(0, 0);
#pragma unroll
    for (int kb = 0; kb < 8; ++kb) {
        const int cur = kb & 1;
        if (kb < 7) {
            stage(kb + 1, cur ^ 1);        // NL loads now in flight
            wait_vmcnt<NL>();              // tile-k loads complete
        } else {
            wait_vmcnt<0>();
        }
        __builtin_amdgcn_s_barrier();      // all waves' tile-k writes visible

        half8 a[MI], bh[4], bl[4];
#pragma unroll
        for (int i = 0; i < MI; ++i)
            a[i] = *(const half8*)&As[cur][((wm + (i << 4) + fr) << 5) + (fq << 3)];
#pragma unroll
        for (int i = 0; i < 4; ++i) {
            const int boff = ((wn + (i << 4) + fr) << 5) + (fq << 3);
            bh[i] = *(const half8*)&BsHi[cur][boff];
            bl[i] = *(const half8*)&BsLo[cur][boff];
        }
#pragma unroll
        for (int mi = 0; mi < MI; ++mi)
#pragma unroll
            for (int ni = 0; ni < 4; ++ni) {
                acc[mi][ni] = __builtin_amdgcn_mfma_f32_16x16x32_f16(a[mi], bh[ni], acc[mi][ni], 0, 0, 0);
                acc[mi][ni] = __builtin_amdgcn_mfma_f32_16x16x32_f16(a[mi], bl[ni], acc[mi][ni], 0, 0, 0);
            }

        if (kb < 7) __builtin_amdgcn_s_barrier();
    }
}

// =======================================================================
// 64x64-tile core, 4 waves all in m; counted-vmcnt; k-stagger.
// =======================================================================
__device__ __forceinline__ void gemm_core64(
    const __half* __restrict__ A16,
    const __half* __restrict__ Bhi, const __half* __restrict__ Blo,
    int m0, int n0, int t, int koff, f32x4 (&acc)[4])
{
    __shared__ short As[2][2048], BsHi[2][2048], BsLo[2][2048];
    const int lane = t & 63, wave = t >> 6;
    const int wm = wave << 4;
    const int fr = lane & 15, fq = lane >> 4;

    auto stage = [&](int kb, int buf) {
        const int kc = (kb + koff) & 7;
        const int rr = wave << 4;          // 16 rows/wave (A and B)
        const size_t ga = (((size_t)(m0 + rr + (lane >> 2))) << 8) + (kc << 5) + ((lane & 3) << 3);
        gld16(A16 + ga, &As[buf][rr << 5]);
        const size_t gb = (((size_t)(kc * 256 + n0 + rr)) << 5) + (lane << 3);
        gld16(Bhi + gb, &BsHi[buf][rr << 5]);
        gld16(Blo + gb, &BsLo[buf][rr << 5]);
    };

    stage(0, 0);
#pragma unroll
    for (int kb = 0; kb < 8; ++kb) {
        const int cur = kb & 1;
        if (kb < 7) {
            stage(kb + 1, cur ^ 1);
            wait_vmcnt<3>();
        } else {
            wait_vmcnt<0>();
        }
        __builtin_amdgcn_s_barrier();

        half8 a = *(const half8*)&As[cur][((wm + fr) << 5) + (fq << 3)];
        half8 bh[4], bl[4];
#pragma unroll
        for (int ni = 0; ni < 4; ++ni) {
            const int boff = (((ni << 4) + fr) << 5) + (fq << 3);
            bh[ni] = *(const half8*)&BsHi[cur][boff];
            bl[ni] = *(const half8*)&BsLo[cur][boff];
        }
#pragma unroll
        for (int ni = 0; ni < 4; ++ni) {
            acc[ni] = __builtin_amdgcn_mfma_f32_16x16x32_f16(a, bh[ni], acc[ni], 0, 0, 0);
            acc[ni] = __builtin_amdgcn_mfma_f32_16x16x32_f16(a, bl[ni], acc[ni], 0, 0, 0);
        }

        if (kb < 7) __builtin_amdgcn_s_barrier();
    }
}

// =======================================================================
// Prep (R4 form): x -> f16 k-blocked + wp; weights -> [kb][n][32] hi/lo.
// =======================================================================
__global__ __launch_bounds__(256) void prep_kernel(
    const float* __restrict__ x, const float* __restrict__ Wqkv,
    const float* __restrict__ Wgate, const float* __restrict__ Wout,
    const float* __restrict__ Wwp, const float* __restrict__ bwp,
    __half* __restrict__ xh,
    __half* __restrict__ wqh, __half* __restrict__ wql,
    __half* __restrict__ wgh, __half* __restrict__ wgl,
    __half* __restrict__ woh, __half* __restrict__ wol,
    float* __restrict__ width, float* __restrict__ sharp)
{
    __shared__ float xs[32][260];
    const int t = threadIdx.x;
    const int blk = blockIdx.x;
    if (blk < 256) {
        const int row0 = blk << 5;
        for (int e = t; e < 2048; e += 256) {
            int r = e >> 6, cc = (e & 63) << 2;
            *(float4*)&xs[r][cc] = *(const float4*)&x[(size_t)(row0 + r) * 256 + cc];
        }
        __syncthreads();
        const int r = t >> 3, kb = t & 7;
        __half hibuf[32];
#pragma unroll
        for (int i = 0; i < 32; ++i)
            hibuf[i] = __float2half(xs[r][(kb << 5) + i]);
        const size_t ob = ((size_t)(kb * 8192 + row0 + r)) << 5;
#pragma unroll
        for (int i = 0; i < 4; ++i)
            *(int4*)&xh[ob + (i << 3)] = *(int4*)&hibuf[i << 3];
        // wp: thread (r, n=kb); 4 accumulators break the 256-FMA dep chain
        float a0 = 0.f, a1 = 0.f, a2 = 0.f, a3 = 0.f;
#pragma unroll 4
        for (int k = 0; k < 256; k += 4) {
            a0 += xs[r][k + 0] * Wwp[(k + 0) * 8 + kb];
            a1 += xs[r][k + 1] * Wwp[(k + 1) * 8 + kb];
            a2 += xs[r][k + 2] * Wwp[(k + 2) * 8 + kb];
            a3 += xs[r][k + 3] * Wwp[(k + 3) * 8 + kb];
        }
        const float acc = (a0 + a1) + (a2 + a3);
        float s = sigm(siluf(acc + bwp[kb]));
        const int row = row0 + r;
        if (kb < 4) width[row * 4 + kb] = s * 4.242640687119285f + 0.5f;  // sqrt(18)
        else        sharp[row * 4 + kb - 4] = s * 9.5f + 0.5f;
    } else {
        const float* W; __half *Whi, *Wlo; int N, nb0, ncnt;
        if (blk < 288)      { W = Wqkv;  Whi = wqh; Wlo = wql; N = 768; nb0 = (blk - 256) * 24; ncnt = 24; }
        else if (blk < 296) { W = Wgate; Whi = wgh; Wlo = wgl; N = 256; nb0 = (blk - 288) * 32; ncnt = 32; }
        else                { W = Wout;  Whi = woh; Wlo = wol; N = 256; nb0 = (blk - 296) * 32; ncnt = 32; }
        for (int j = 0; j < ncnt; ++j)
            xs[j][t] = W[(size_t)t * N + nb0 + j];   // t = k row
        __syncthreads();
        for (int c = t; c < ncnt * 8; c += 256) {
            const int j = c >> 3, kb = c & 7;
            __half hibuf[32], lobuf[32];
#pragma unroll
            for (int i = 0; i < 32; ++i) {
                float v = xs[j][(kb << 5) + i];
                __half hv = __float2half(v);
                hibuf[i] = hv;
                lobuf[i] = __float2half(v - __half2float(hv));
            }
            const size_t ob = ((size_t)(kb * N + nb0 + j)) << 5;
#pragma unroll
            for (int i = 0; i < 4; ++i) {
                *(int4*)&Whi[ob + (i << 3)] = *(int4*)&hibuf[i << 3];
                *(int4*)&Wlo[ob + (i << 3)] = *(int4*)&lobuf[i << 3];
            }
        }
    }
}

// =======================================================================
// qkv GEMM (64x128 tiles, 768 blocks = 3/CU, k-staggered) + fused silu ->
// rmsnorm -> RoPE(pos=head) -> f16 stores.
// =======================================================================
__global__ __launch_bounds__(256, 3) void gemm_qkv(
    const __half* __restrict__ xh,
    const __half* __restrict__ wqh, const __half* __restrict__ wql,
    const float* __restrict__ wq, const float* __restrict__ wk,
    __half* __restrict__ qh, __half* __restrict__ kh, __half* __restrict__ vh)
{
    const int t  = threadIdx.x;
    const int m0 = blockIdx.y << 6, n0 = blockIdx.x << 7;
    f32x4 acc[2][4] = {};
    gemm_core16<2, 0>(xh, wqh, wql, 768, m0, n0, t, blockIdx.y & 7, acc);

    const int lane = t & 63, wave = t >> 6;
    const int wm = (wave >> 1) << 5, wn = (wave & 1) << 6;
    const int fr = lane & 15, fq = lane >> 4;
    const int gc0 = n0 + wn;
    const int seg = gc0 >> 8;          // 0=q, 1=k, 2=v
    const int h   = (gc0 >> 6) & 3;
    const int hc0 = h << 6;

#pragma unroll
    for (int mi = 0; mi < 2; ++mi)
#pragma unroll
        for (int ni = 0; ni < 4; ++ni)
#pragma unroll
            for (int r = 0; r < 4; ++r)
                acc[mi][ni][r] = siluf(acc[mi][ni][r]);

    if (seg == 2) {
#pragma unroll
        for (int mi = 0; mi < 2; ++mi)
#pragma unroll
            for (int r = 0; r < 4; ++r) {
                const size_t row = m0 + wm + (mi << 4) + (fq << 2) + r;
#pragma unroll
                for (int ni = 0; ni < 4; ++ni)
                    vh[row * 256 + hc0 + (ni << 4) + fr] = __float2half(acc[mi][ni][r]);
            }
    } else {
        const float* wnorm = seg ? wk : wq;
        float wv[4];
#pragma unroll
        for (int ni = 0; ni < 4; ++ni) wv[ni] = wnorm[(ni << 4) + fr];
        float cs[2], sn[2];
#pragma unroll
        for (int j = 0; j < 2; ++j) {
            const int d = (j << 4) + fr;
            const float freq = powf(10000.f, -(float)d * (1.f / 32.f));
            const float ang = (float)h * freq;    // pos = arange(H) reference quirk
            cs[j] = cosf(ang); sn[j] = sinf(ang);
        }
        __half* dstbase = (seg ? kh : qh);
#pragma unroll
        for (int mi = 0; mi < 2; ++mi)
#pragma unroll
            for (int r = 0; r < 4; ++r) {
                float ss = acc[mi][0][r] * acc[mi][0][r] + acc[mi][1][r] * acc[mi][1][r]
                         + acc[mi][2][r] * acc[mi][2][r] + acc[mi][3][r] * acc[mi][3][r];
                ss += __shfl_xor(ss, 1); ss += __shfl_xor(ss, 2);
                ss += __shfl_xor(ss, 4); ss += __shfl_xor(ss, 8);
                const float rinv = 1.f / sqrtf(ss * (1.f / 64.f) + 1e-6f);
                float xv[4];
#pragma unroll
                for (int ni = 0; ni < 4; ++ni) xv[ni] = acc[mi][ni][r] * rinv * wv[ni];
                const float o0 = xv[0] * cs[0] - xv[2] * sn[0];
                const float o2 = xv[0] * sn[0] + xv[2] * cs[0];
                const float o1 = xv[1] * cs[1] - xv[3] * sn[1];
                const float o3 = xv[1] * sn[1] + xv[3] * cs[1];
                const size_t row = m0 + wm + (mi << 4) + (fq << 2) + r;
                __half* dst = dstbase + row * 256 + hc0;
                dst[fr]      = __float2half(o0);
                dst[16 + fr] = __float2half(o1);
                dst[32 + fr] = __float2half(o2);
                dst[48 + fr] = __float2half(o3);
            }
    }
}

// ---- gate GEMM (64x64 tiles, 512 blocks, k-staggered) + o-rmsnorm + merge ----
__global__ __launch_bounds__(256, 2) void gemm_gate(
    const __half* __restrict__ vh,
    const __half* __restrict__ wgh, const __half* __restrict__ wgl,
    const float* __restrict__ bias, const float* __restrict__ attn_o,
    const float* __restrict__ sumsq4, const float* __restrict__ w_onorm,
    __half* __restrict__ mh)
{
    const int t  = threadIdx.x;
    const int m0 = blockIdx.y << 6, n0 = blockIdx.x << 6;
    f32x4 acc[4] = {};
    gemm_core64(vh, wgh, wgl, m0, n0, t, blockIdx.y & 7, acc);

    const int lane = t & 63, wave = t >> 6;
    const int wm = wave << 4;
    const int fr = lane & 15, fq = lane >> 4;

    float rmsf[4];
#pragma unroll
    for (int r = 0; r < 4; ++r) {
        const int m = m0 + wm + (fq << 2) + r;
        float4 s4 = *(const float4*)&sumsq4[(size_t)m * 4];
        rmsf[r] = 1.f / sqrtf((s4.x + s4.y + s4.z + s4.w) * (1.f / 256.f) + 1e-6f);
    }

#pragma unroll
    for (int ni = 0; ni < 4; ++ni) {
        const int n  = n0 + (ni << 4) + fr;
        const int mb = m0 + wm + (fq << 2);
        const float bb  = bias[n];
        const float won = w_onorm[n];
#pragma unroll
        for (int r = 0; r < 4; ++r) {
            const int m = mb + r;
            const float g  = sigm(siluf(acc[ni][r] + bb));
            const float vv = __half2float(vh[(size_t)m * 256 + n]);
            const float oo = attn_o[(size_t)m * 256 + n] * rmsf[r] * won;
            mh[(size_t)m * 256 + n] = __float2half(g * vv + (1.f - g) * oo);
        }
    }
}

// ---- final GEMM (64x64 tiles, 512 blocks, k-staggered): out = silu(mh @ W_out) ----
__global__ __launch_bounds__(256, 2) void gemm_out(
    const __half* __restrict__ mh,
    const __half* __restrict__ woh, const __half* __restrict__ wol,
    float* __restrict__ out)
{
    const int t  = threadIdx.x;
    const int m0 = blockIdx.y << 6, n0 = blockIdx.x << 6;
    f32x4 acc[4] = {};
    gemm_core64(mh, woh, wol, m0, n0, t, blockIdx.y & 7, acc);

    const int lane = t & 63, wave = t >> 6;
    const int wm = wave << 4;
    const int fr = lane & 15, fq = lane >> 4;
#pragma unroll
    for (int ni = 0; ni < 4; ++ni) {
        const int n  = n0 + (ni << 4) + fr;
        const int mb = m0 + wm + (fq << 2);
#pragma unroll
        for (int r = 0; r < 4; ++r)
            out[(size_t)(mb + r) * 256 + n] = siluf(acc[ni][r]);
    }
}

// =======================================================================
// Patch-GEMM local attention.  R17: staging widened to 8 B/lane
// (13 passes x 16 rows; rows 196..207 zeroed via ok=false -> both
// zero-fill passes deleted: QK/PV provably never read past col 207).
// Barrier #3 -> lgkmcnt(0): PV reads only own-wave P rows + Vt (fenced
// by barrier #1); own-wave LDS write->read needs no workgroup barrier.
// =======================================================================
#define PT 216   // P / Vt row stride (halves)

__global__ __launch_bounds__(256, 2) void attn_mfma(
    const __half* __restrict__ qh, const __half* __restrict__ kh,
    const __half* __restrict__ vh, const float* __restrict__ width,
    const float* __restrict__ sharp, float* __restrict__ attn_o,
    float* __restrict__ sumsq4)
{
    __shared__ short smem[27648];          // 55296 B
    short* Ksh = smem;                     // [208][64] chunk-swizzled; overlaid by P [64][PT]
    short* Psh = smem;
    short* Vt  = smem + 13824;             // [64 d][PT]

    const int t = threadIdx.x;
    const int lane = t & 63, wave = t >> 6;
    const int fr = lane & 15, fq = lane >> 4;
    const int patch = blockIdx.x, h = blockIdx.y, b = blockIdx.z;
    const int pr0 = (patch >> 3) << 3, pc0 = (patch & 7) << 3;
    const int t0 = (wave * 28) >> 4;       // first n-tile of this wave's window

    float wd[4], sh[4]; int lq[4];
#pragma unroll
    for (int r = 0; r < 4; ++r) {
        const int q = (wave << 4) + (fq << 2) + r;
        lq[r] = (pr0 + (q >> 3)) * 64 + pc0 + (q & 7);
        wd[r] = width[((b << 12) + lq[r]) * 4 + h];
        sh[r] = sharp[((b << 12) + lq[r]) * 4 + h];
    }

    // ---- Q straight into A-frags ----
    const int qrow = (wave << 4) + fr;
    const int lqr = (pr0 + (qrow >> 3)) * 64 + pc0 + (qrow & 7);
    const __half* qptr = qh + (((size_t)(b << 12) + lqr) << 8) + (h << 6) + (fq << 3);
    half8 a0 = *(const half8*)qptr;
    half8 a1 = *(const half8*)(qptr + 32);

    // ---- K/V staging: 13 passes x 16 rows, 8 B/lane ----
    const int srow = t >> 4;               // row within pass
    const int d4 = (t & 15) << 2;          // 4 halves = 8 B per lane
    const size_t cbase = (((size_t)b << 12) * 256) + (size_t)h * 64 + d4;

    u32x2 kb2[13], vb2[13];
#pragma unroll
    for (int p = 0; p < 13; ++p) {
        const int prow = (p << 4) + srow;  // 0..207
        const int pi = prow / 14, pj = prow - pi * 14;
        const int gr = pr0 - 3 + pi, gc = pc0 - 3 + pj;
        const bool ok = (prow < 196) & ((unsigned)gr < 64u) & ((unsigned)gc < 64u);
        const int grc = min(max(gr, 0), 63), gcc = min(max(gc, 0), 63);
        const size_t off = cbase + (size_t)(grc * 64 + gcc) * 256;
        u32x2 kv = *(const u32x2*)(kh + off);
        u32x2 vv = *(const u32x2*)(vh + off);
        const u32x2 z = {0u, 0u};
        kb2[p] = ok ? kv : z;
        vb2[p] = ok ? vv : z;
    }

    const int chunk = d4 >> 3, dlo = d4 & 7;   // 8 B within one 16 B chunk
#pragma unroll
    for (int p = 0; p < 13; ++p) {
        const int prow = (p << 4) + srow;
        *(u32x2*)&Ksh[(prow << 6) + ((chunk ^ (prow & 7)) << 3) + dlo] = kb2[p];
        Vt[(d4)     * PT + prow] = (short)(vb2[p].x & 0xffffu);
        Vt[(d4 + 1) * PT + prow] = (short)(vb2[p].x >> 16);
        Vt[(d4 + 2) * PT + prow] = (short)(vb2[p].y & 0xffffu);
        Vt[(d4 + 3) * PT + prow] = (short)(vb2[p].y >> 16);
    }
    __syncthreads();

    // ---- QK^T: 8 windowed n-tiles of 16 positions ----
    f32x4 sc[8];
#pragma unroll
    for (int tl = 0; tl < 8; ++tl) {
        const int kr = ((t0 + tl) << 4) + fr;
        half8 b0 = *(const half8*)&Ksh[(kr << 6) + (((0 + fq) ^ (kr & 7)) << 3)];
        half8 b1 = *(const half8*)&Ksh[(kr << 6) + (((4 + fq) ^ (kr & 7)) << 3)];
        f32x4 z = {0.f, 0.f, 0.f, 0.f};
        z = __builtin_amdgcn_mfma_f32_16x16x32_f16(a0, b0, z, 0, 0, 0);
        sc[tl] = __builtin_amdgcn_mfma_f32_16x16x32_f16(a1, b1, z, 0, 0, 0);
    }

    // ---- mask + softmax ----
    float mx[4] = {-3e38f, -3e38f, -3e38f, -3e38f};
#pragma unroll
    for (int tl = 0; tl < 8; ++tl) {
        const int p = ((t0 + tl) << 4) + fr;
        const int pi = p / 14, pj = p - pi * 14;
        const bool pvld = p < 196;
#pragma unroll
        for (int r = 0; r < 4; ++r) {
            const int q = (wave << 4) + (fq << 2) + r;
            const int di = pi - 3 - ((q >> 3) & 7), dj = pj - 3 - (q & 7);
            const bool win = pvld & ((unsigned)(di + 3) <= 6u) & ((unsigned)(dj + 3) <= 6u);
            const float rel = sqrtf((float)(di * di + dj * dj));
            const float mk = sigm((wd[r] - rel) * sh[r]);
            float s = sc[tl][r] * 0.125f - (1.f - mk) * 10000.f;
            s = win ? s : -3e38f;
            sc[tl][r] = s;
            mx[r] = fmaxf(mx[r], s);
        }
    }
#pragma unroll
    for (int r = 0; r < 4; ++r) {
        mx[r] = fmaxf(mx[r], __shfl_xor(mx[r], 1));
        mx[r] = fmaxf(mx[r], __shfl_xor(mx[r], 2));
        mx[r] = fmaxf(mx[r], __shfl_xor(mx[r], 4));
        mx[r] = fmaxf(mx[r], __shfl_xor(mx[r], 8));
    }
    float sm[4] = {0.f, 0.f, 0.f, 0.f};
#pragma unroll
    for (int tl = 0; tl < 8; ++tl)
#pragma unroll
        for (int r = 0; r < 4; ++r) {
            const float e = __expf(sc[tl][r] - mx[r]);
            sc[tl][r] = e; sm[r] += e;
        }
#pragma unroll
    for (int r = 0; r < 4; ++r) {
        sm[r] += __shfl_xor(sm[r], 1);
        sm[r] += __shfl_xor(sm[r], 2);
        sm[r] += __shfl_xor(sm[r], 4);
        sm[r] += __shfl_xor(sm[r], 8);
        sm[r] = 1.f / sm[r];
    }

    __syncthreads();   // all waves' Ksh frag reads done before P overwrites
#pragma unroll
    for (int tl = 0; tl < 8; ++tl)
#pragma unroll
        for (int r = 0; r < 4; ++r) {
            __half pv = __float2half(sc[tl][r] * sm[r]);
            Psh[((wave << 4) + (fq << 2) + r) * PT + ((t0 + tl) << 4) + fr] = *(short*)&pv;
        }
    // PV reads only own-wave P rows (pra in own 16-row band) + Vt (fenced
    // by barrier #1): own-wave LDS write->read ordering via lgkmcnt only.
    asm volatile("s_waitcnt lgkmcnt(0)" ::: "memory");
    __builtin_amdgcn_sched_barrier(0);

    // ---- PV: K = 128 (4x32), windowed at t0*16 ----
    f32x4 o[4] = {};
    const int pra = (wave << 4) + fr;
    const int cb = t0 << 4;
#pragma unroll
    for (int s = 0; s < 4; ++s) {
        half8 pa = *(const half8*)&Psh[pra * PT + cb + (fq << 3) + (s << 5)];
#pragma unroll
        for (int dt = 0; dt < 4; ++dt) {
            half8 vbf = *(const half8*)&Vt[((dt << 4) + fr) * PT + cb + (fq << 3) + (s << 5)];
            o[dt] = __builtin_amdgcn_mfma_f32_16x16x32_f16(pa, vbf, o[dt], 0, 0, 0);
        }
    }

#pragma unroll
    for (int r = 0; r < 4; ++r) {
        float ss = o[0][r]*o[0][r] + o[1][r]*o[1][r] + o[2][r]*o[2][r] + o[3][r]*o[3][r];
        ss += __shfl_xor(ss, 1); ss += __shfl_xor(ss, 2);
        ss += __shfl_xor(ss, 4); ss += __shfl_xor(ss, 8);
        const size_t rowb = (((size_t)(b << 12) + lq[r]) << 8) + h * 64;
#pragma unroll
        for (int dt = 0; dt < 4; ++dt)
            attn_o[rowb + (dt << 4) + fr] = o[dt][r];
        if (fr == 0) sumsq4[(((b << 12) + lq[r]) << 2) + h] = ss;
    }
}

extern "C" void kernel_launch(void* const* d_in, const int* in_sizes, int n_in,
                              void* d_out, int out_size, void* d_ws, size_t ws_size,
                              hipStream_t stream)
{
    const float* x      = (const float*)d_in[0];
    const float* W_qkv  = (const float*)d_in[1];
    const float* w_qn   = (const float*)d_in[2];
    const float* w_kn   = (const float*)d_in[3];
    const float* W_wp   = (const float*)d_in[4];
    const float* b_wp   = (const float*)d_in[5];
    const float* w_on   = (const float*)d_in[6];
    const float* W_out  = (const float*)d_in[7];
    const float* W_gate = (const float*)d_in[8];
    const float* b_gate = (const float*)d_in[9];
    float* out = (float*)d_out;

    __half* ws16 = (__half*)d_ws;
    __half* xh  = ws16;                    // [8][8192][32]
    __half* wqh = xh  + 2097152;           // [8][768][32]
    __half* wql = wqh + 196608;
    __half* wgh = wql + 196608;            // [8][256][32]
    __half* wgl = wgh + 65536;
    __half* woh = wgl + 65536;
    __half* wol = woh + 65536;
    __half* qhp = wol + 65536;             // [8192][256]
    __half* khp = qhp + 2097152;
    __half* vhp = khp + 2097152;
    __half* mh  = vhp + 2097152;
    float* attn_o = (float*)(mh + 2097152);  // [8192][256] f32
    float* widthp = attn_o + 2097152;
    float* sharpp = widthp + 32768;
    float* sumsq4 = sharpp + 32768;

    // x -> f16 blocked + wp; weights -> transposed f16 hi/lo blocked
    prep_kernel<<<304, 256, 0, stream>>>(x, W_qkv, W_gate, W_out, W_wp, b_wp,
                                         xh, wqh, wql, wgh, wgl, woh, wol,
                                         widthp, sharpp);
    // qkv GEMM (2-term, pipelined, k-staggered) + fused silu/rmsnorm/rope
    gemm_qkv<<<dim3(6, 128), 256, 0, stream>>>(xh, wqh, wql, w_qn, w_kn,
                                               qhp, khp, vhp);
    // patch-GEMM local attention (raw O + sumsq)
    attn_mfma<<<dim3(64, 4, 2), 256, 0, stream>>>(qhp, khp, vhp, widthp, sharpp,
                                                  attn_o, sumsq4);
    // gate gemm (64x64, 512 blocks, k-staggered) + fused o-rmsnorm + merge
    gemm_gate<<<dim3(4, 128), 256, 0, stream>>>(vhp, wgh, wgl, b_gate,
                                                attn_o, sumsq4, w_on, mh);
    // final silu(merged @ W_out) (64x64, 512 blocks, k-staggered)
    gemm_out<<<dim3(4, 128), 256, 0, stream>>>(mh, woh, wol, out);
}